// Round 1
// 85.823 us; speedup vs baseline: 1.0505x; 1.0505x over previous
//
#include <hip/hip_runtime.h>
#include <math.h>

#define NPTS 8192
#define QPB  32           // queries per fused block
#define NCHUNK 8          // candidate chunks per fused block
#define NBLK_F 256        // fused kernel blocks (32 queries each)

__device__ __forceinline__ float fmax3(float a, float b, float c) {
    return fmaxf(fmaxf(a, b), c);
}

// Forced v_max3_f32 with abs modifiers (R10/R11-proven bit-correct).
__device__ __forceinline__ float max3abs(float a, float b, float c) {
    float r;
    asm("v_max3_f32 %0, |%1|, |%2|, |%3|" : "=v"(r) : "v"(a), "v"(b), "v"(c));
    return r;
}
__device__ __forceinline__ float max3vaa(float m, float b, float c) {
    float r;
    asm("v_max3_f32 %0, %1, |%2|, |%3|" : "=v"(r) : "v"(m), "v"(b), "v"(c));
    return r;
}
__device__ __forceinline__ float max3v(float a, float b, float c) {
    float r;
    asm("v_max3_f32 %0, %1, %2, %3" : "=v"(r) : "v"(a), "v"(b), "v"(c));
    return r;
}

// 32-dim Chebyshev: 32 subs + 16 max3/max ops.
__device__ __forceinline__ float cheb32_pair(const float* __restrict__ q,
                                             const float* __restrict__ p) {
    float s[32];
    #pragma unroll
    for (int k = 0; k < 32; ++k) s[k] = q[k] - p[k];
    float l[10];
    #pragma unroll
    for (int g = 0; g < 10; ++g) l[g] = max3abs(s[3*g], s[3*g+1], s[3*g+2]);
    float c3 = max3vaa(l[9], s[30], s[31]);
    float c0 = max3v(l[0], l[1], l[2]);
    float c1 = max3v(l[3], l[4], l[5]);
    float c2 = max3v(l[6], l[7], l[8]);
    return fmaxf(max3v(c0, c1, c2), c3);
}

// Branchless top-4 insert, indices on levels 0-2 (R8-proven).
__device__ __forceinline__ void ins4p(float d, int di,
    float& t0, float& t1, float& t2, float& t3,
    int& i0, int& i1, int& i2)
{
    bool c0 = d > t0;
    float v1 = fminf(t0, d); int j1 = c0 ? i0 : di;
    t0 = fmaxf(t0, d);       i0 = c0 ? di : i0;
    bool c1 = v1 > t1;
    float v2 = fminf(t1, v1); int j2 = c1 ? i1 : j1;
    t1 = fmaxf(t1, v1);       i1 = c1 ? j1 : i1;
    bool c2 = v2 > t2;
    float v3 = fminf(t2, v2);
    t2 = fmaxf(t2, v2);       i2 = c2 ? j2 : i2;
    t3 = fmaxf(t3, v3);
}

// Branchless top-4 insert with indices on ALL 4 levels (for extremes).
__device__ __forceinline__ void ins4full(float d, int di,
    float& t0, float& t1, float& t2, float& t3,
    int& i0, int& i1, int& i2, int& i3)
{
    bool c0 = d > t0;
    float v1 = fminf(t0, d); int j1 = c0 ? i0 : di;
    t0 = fmaxf(t0, d);       i0 = c0 ? di : i0;
    bool c1 = v1 > t1;
    float v2 = fminf(t1, v1); int j2 = c1 ? i1 : j1;
    t1 = fmaxf(t1, v1);       i1 = c1 ? j1 : i1;
    bool c2 = v2 > t2;
    float v3 = fminf(t2, v2); int j3 = c2 ? i2 : j2;
    t2 = fmaxf(t2, v2);       i2 = c2 ? j2 : i2;
    bool c3 = v3 > t3;
    t3 = fmaxf(t3, v3);       i3 = c3 ? j3 : i3;
}

__device__ double digamma_d(double x) {
    double r = 0.0;
    while (x < 6.0) { r -= 1.0 / x; x += 1.0; }
    double f = 1.0 / (x * x);
    double t = f * (1.0/12.0 - f * (1.0/120.0 - f * (1.0/252.0 - f * (1.0/240.0 - f * (1.0/132.0)))));
    return r + log(x) - 0.5 / x - t;
}

__device__ __forceinline__ void load_query(float* qv, const float* __restrict__ x,
                                           const float* __restrict__ y, int q)
{
    const float4* qx4 = reinterpret_cast<const float4*>(x) + (size_t)q * 4;
    const float4* qy4 = reinterpret_cast<const float4*>(y) + (size_t)q * 4;
    #pragma unroll
    for (int i = 0; i < 4; ++i) {
        float4 v = qx4[i];
        qv[4*i+0] = v.x; qv[4*i+1] = v.y; qv[4*i+2] = v.z; qv[4*i+3] = v.w;
        float4 w = qy4[i];
        qv[16+4*i+0] = w.x; qv[16+4*i+1] = w.y; qv[16+4*i+2] = w.z; qv[16+4*i+3] = w.w;
    }
}

// ---------------------------------------------------------------------------
// K0: per-dim extremes. ONE BLOCK PER DIM (32 blocks x 256 threads).
// THEOREM (exact, R12-validated absmax 0.0): the global top-4 values and
// top-3 indices lie in the union of per-dim 4-lowest/4-highest points.
// Block 0 additionally zeroes acc + ticket (replaces the hipMemsetAsync
// dispatch; stream order guarantees visibility to the fused kernel).
// ---------------------------------------------------------------------------
__global__ __launch_bounds__(256) void extremes_kernel(
    const float* __restrict__ x, const float* __restrict__ y,
    unsigned short* __restrict__ cand_raw,
    double* __restrict__ acc, unsigned* __restrict__ ticket)
{
    const int dim  = blockIdx.x;             // 0..31
    const int tid  = threadIdx.x;
    const int lane = tid & 63;
    const int wave = tid >> 6;               // 0..3
    if (dim == 0 && tid == 0) { acc[0] = 0.0; ticket[0] = 0u; }
    const float* base = (dim < 16) ? (x + dim) : (y + (dim - 16));

    float h0=-3.4e38f,h1=-3.4e38f,h2=-3.4e38f,h3=-3.4e38f;  // top-4 max
    int   a0=0,a1=0,a2=0,a3=0;
    float l0=-3.4e38f,l1=-3.4e38f,l2=-3.4e38f,l3=-3.4e38f;  // top-4 of (-v) = min
    int   b0=0,b1=0,b2=0,b3=0;
    #pragma unroll 8
    for (int j = tid; j < NPTS; j += 256) {
        float v = base[(size_t)j * 16];
        ins4full( v, j, h0,h1,h2,h3, a0,a1,a2,a3);
        ins4full(-v, j, l0,l1,l2,l3, b0,b1,b2,b3);
    }
    #pragma unroll
    for (int off = 32; off > 0; off >>= 1) {
        float m0=__shfl_xor(h0,off), m1=__shfl_xor(h1,off),
              m2=__shfl_xor(h2,off), m3=__shfl_xor(h3,off);
        int   c0=__shfl_xor(a0,off), c1=__shfl_xor(a1,off),
              c2=__shfl_xor(a2,off), c3=__shfl_xor(a3,off);
        ins4full(m0,c0, h0,h1,h2,h3, a0,a1,a2,a3);
        ins4full(m1,c1, h0,h1,h2,h3, a0,a1,a2,a3);
        ins4full(m2,c2, h0,h1,h2,h3, a0,a1,a2,a3);
        ins4full(m3,c3, h0,h1,h2,h3, a0,a1,a2,a3);
        float n0=__shfl_xor(l0,off), n1=__shfl_xor(l1,off),
              n2=__shfl_xor(l2,off), n3=__shfl_xor(l3,off);
        int   d0=__shfl_xor(b0,off), d1=__shfl_xor(b1,off),
              d2=__shfl_xor(b2,off), d3=__shfl_xor(b3,off);
        ins4full(n0,d0, l0,l1,l2,l3, b0,b1,b2,b3);
        ins4full(n1,d1, l0,l1,l2,l3, b0,b1,b2,b3);
        ins4full(n2,d2, l0,l1,l2,l3, b0,b1,b2,b3);
        ins4full(n3,d3, l0,l1,l2,l3, b0,b1,b2,b3);
    }
    __shared__ float shv[4][8];
    __shared__ int   shi[4][8];
    if (lane == 0) {
        shv[wave][0]=h0; shv[wave][1]=h1; shv[wave][2]=h2; shv[wave][3]=h3;
        shv[wave][4]=l0; shv[wave][5]=l1; shv[wave][6]=l2; shv[wave][7]=l3;
        shi[wave][0]=a0; shi[wave][1]=a1; shi[wave][2]=a2; shi[wave][3]=a3;
        shi[wave][4]=b0; shi[wave][5]=b1; shi[wave][6]=b2; shi[wave][7]=b3;
    }
    __syncthreads();
    if (tid == 0) {
        #pragma unroll
        for (int w = 1; w < 4; ++w) {
            #pragma unroll
            for (int e = 0; e < 4; ++e) {
                ins4full(shv[w][e],   shi[w][e],   h0,h1,h2,h3, a0,a1,a2,a3);
                ins4full(shv[w][4+e], shi[w][4+e], l0,l1,l2,l3, b0,b1,b2,b3);
            }
        }
        cand_raw[dim*8+0] = (unsigned short)a0;
        cand_raw[dim*8+1] = (unsigned short)a1;
        cand_raw[dim*8+2] = (unsigned short)a2;
        cand_raw[dim*8+3] = (unsigned short)a3;
        cand_raw[dim*8+4] = (unsigned short)b0;
        cand_raw[dim*8+5] = (unsigned short)b1;
        cand_raw[dim*8+6] = (unsigned short)b2;
        cand_raw[dim*8+7] = (unsigned short)b3;
    }
}

// ---------------------------------------------------------------------------
// KF: FUSED dedupe + candidate-kNN + merge + exact 3-candidate check +
// digamma + block reduce + last-block finalization.
//
// grid: 256 blocks x 256 threads. Each block owns 32 queries; thread
// (ql, ck) computes query ql's top-4 over candidate chunk ck (32 cands).
//
// Dedupe is re-derived per block DETERMINISTICALLY: LDS bitmask (atomicOr,
// order-independent) -> compaction sorted by point index (popc prefix sum).
// All 256 blocks therefore agree on the identical chunk partition.
// Tie-breaking differences vs the old racy compaction are count-invariant:
// a tied joint value has val == t3 == rq, so `act` is false either way.
//
// Final reduction: after each block's atomicAdd(acc,·), thread 0 fences and
// takes a ticket; the last block reads acc (device-scope atomic, coherent
// across XCDs) and writes the answer. Replaces final_kernel.
// ---------------------------------------------------------------------------
__global__ __launch_bounds__(256) void fused_kernel(
    const float* __restrict__ x, const float* __restrict__ y,
    const unsigned short* __restrict__ cand_raw,
    double* __restrict__ acc, unsigned* __restrict__ ticket,
    float* __restrict__ out)
{
    __shared__ unsigned       mask[NPTS / 32];   // 1 KB bitmask
    __shared__ unsigned short slist[256];        // sorted compacted candidates
    __shared__ int            wsum[4];
    __shared__ int            s_cnt;
    __shared__ float4         pc4[256 * 8];      // 32 KB candidate coords
    __shared__ float4         sv[NCHUNK][QPB];
    __shared__ ushort4        si8[NCHUNK][QPB];

    const int tid  = threadIdx.x;
    const int lane = tid & 63;
    const int wv   = tid >> 6;

    // ---- deterministic dedupe: bitmask -> sorted compaction ----
    mask[tid]  = 0u;
    slist[tid] = 0;                              // safe default for pos >= cnt
    __syncthreads();
    {
        unsigned short c = cand_raw[tid];
        atomicOr(&mask[c >> 5], 1u << (c & 31));
    }
    __syncthreads();
    unsigned w = mask[tid];                      // thread t owns 32-point word t
    int cw = __popc(w);
    int pfx = cw;                                // inclusive wave prefix
    #pragma unroll
    for (int off = 1; off < 64; off <<= 1) {
        int n = __shfl_up(pfx, off);
        if (lane >= off) pfx += n;
    }
    if (lane == 63) wsum[wv] = pfx;
    __syncthreads();
    int base = 0;
    #pragma unroll
    for (int i = 0; i < 3; ++i) base += (i < wv) ? wsum[i] : 0;
    int pos = base + pfx - cw;                   // exclusive prefix
    while (w) {
        int b = __ffs(w) - 1;
        w &= w - 1;
        slist[pos++] = (unsigned short)(tid * 32 + b);
    }
    if (tid == 255) s_cnt = base + pfx;          // total count
    __syncthreads();
    const int cnt = s_cnt;

    // ---- stage candidate coords into LDS (float4, coalesced) ----
    #pragma unroll
    for (int it = 0; it < 8; ++it) {
        int e = it * 256 + tid;                  // 2048 float4s total
        int cand = e >> 3, quad = e & 7;
        int j = slist[cand];
        const float4* src = (quad < 4)
            ? (reinterpret_cast<const float4*>(x) + (size_t)j * 4 + quad)
            : (reinterpret_cast<const float4*>(y) + (size_t)j * 4 + (quad - 4));
        pc4[cand * 8 + quad] = *src;
    }

    const int ql = tid & (QPB - 1);              // query within block
    const int ck = tid >> 5;                     // candidate chunk 0..7
    const int q  = blockIdx.x * QPB + ql;
    float qv[32];
    load_query(qv, x, y, q);
    __syncthreads();

    // ---- per-chunk top-4 over this thread's 32 candidates ----
    const float* pc = reinterpret_cast<const float*>(pc4);
    float t0=-1.f,t1=-1.f,t2=-1.f,t3=-1.f;
    int i0=0,i1=0,i2=0;
    for (int jj = 0; jj < 32; ++jj) {
        int idx = ck * 32 + jj;
        if (idx >= cnt) break;                   // sorted compaction: prefix holds
        float m = cheb32_pair(qv, pc + idx * 32);
        ins4p(m, slist[idx], t0, t1, t2, t3, i0, i1, i2);
    }
    sv[ck][ql]  = make_float4(t0, t1, t2, t3);
    si8[ck][ql] = make_ushort4((unsigned short)i0, (unsigned short)i1,
                               (unsigned short)i2, 0);
    __syncthreads();

    // ---- merge 8 chunks + exact check + digamma (ck == 0 only) ----
    if (ck == 0) {
        #pragma unroll
        for (int c = 1; c < NCHUNK; ++c) {
            float4  v  = sv[c][ql];
            ushort4 id = si8[c][ql];
            ins4p(v.x, id.x, t0,t1,t2,t3, i0,i1,i2);
            ins4p(v.y, id.y, t0,t1,t2,t3, i0,i1,i2);
            ins4p(v.z, id.z, t0,t1,t2,t3, i0,i1,i2);
            ins4p(v.w, 0,    t0,t1,t2,t3, i0,i1,i2);  // 4th: value-only (safe)
        }
        const float rq = t3 - 1e-15f;  // == t3 bit-exact in f32 (reference fidelity)

        float vals[3] = { t0, t1, t2 };
        int   idxs[3] = { i0, i1, i2 };
        int missx = 0, missy = 0;
        #pragma unroll
        for (int k = 0; k < 3; ++k) {
            const int j = idxs[k];
            const float4* px4 = reinterpret_cast<const float4*>(x) + (size_t)j * 4;
            const float4* py4 = reinterpret_cast<const float4*>(y) + (size_t)j * 4;
            float mx = 0.0f, my = 0.0f;
            #pragma unroll
            for (int i = 0; i < 4; ++i) {
                float4 a = px4[i];
                mx = fmax3(mx, fmax3(fabsf(qv[4*i+0]-a.x), fabsf(qv[4*i+1]-a.y),
                                     fabsf(qv[4*i+2]-a.z)), fabsf(qv[4*i+3]-a.w));
                float4 b = py4[i];
                my = fmax3(my, fmax3(fabsf(qv[16+4*i+0]-b.x), fabsf(qv[16+4*i+1]-b.y),
                                     fabsf(qv[16+4*i+2]-b.z)), fabsf(qv[16+4*i+3]-b.w));
            }
            const bool act = vals[k] > rq;   // only strict-greater joints can miss
            missx += (act && (mx > rq)) ? 1 : 0;
            missy += (act && (my > rq)) ? 1 : 0;
        }
        const int nx = NPTS - missx;
        const int ny = NPTS - missy;
        double d = digamma_d((double)nx) + digamma_d((double)ny);
        #pragma unroll
        for (int off = 16; off > 0; off >>= 1)
            d += __shfl_down(d, off, 32);
        if (ql == 0) {
            atomicAdd(acc, d);
            __threadfence();
            unsigned t = atomicAdd(ticket, 1u);
            if (t == (unsigned)gridDim.x - 1u) {
                // all 256 block sums are visible (device-scope atomics)
                double total = atomicAdd(acc, 0.0);
                double ans = digamma_d((double)NPTS) + digamma_d(4.0)
                           - total / (double)NPTS;
                out[0] = (float)ans;
            }
        }
    }
}

// ---------------------------------------------------------------------------
extern "C" void kernel_launch(void* const* d_in, const int* in_sizes, int n_in,
                              void* d_out, int out_size, void* d_ws, size_t ws_size,
                              hipStream_t stream)
{
    (void)in_sizes; (void)n_in; (void)out_size; (void)ws_size;
    const float* x = (const float*)d_in[0];
    const float* y = (const float*)d_in[1];
    float* out = (float*)d_out;

    // workspace: acc f64 @0 | ticket u32 @8 | cand_raw 256 u16 @16
    char* ws = (char*)d_ws;
    double* acc = (double*)ws;
    unsigned* ticket = (unsigned*)(ws + 8);
    unsigned short* cand_raw = (unsigned short*)(ws + 16);

    extremes_kernel<<<32, 256, 0, stream>>>(x, y, cand_raw, acc, ticket);
    fused_kernel<<<NBLK_F, 256, 0, stream>>>(x, y, cand_raw, acc, ticket, out);
}